// Round 16
// baseline (182.498 us; speedup 1.0000x reference)
//
#include <hip/hip_runtime.h>
#include <hip/hip_bf16.h>
#include <math.h>

#define NCLS 21
#define WH 1681          // 41*41
#define WHP 1684         // padded row stride for pacc (16B-aligned float4 stores)
#define BS 4
#define CIN 2048
#define NSRC 1089        // 33*33
#define KPOS 18432       // 2048*9
#define MR 192           // 21*9=189 padded to 192
#define HS 836352        // one k-split slab of Hp
#define NT 53            // ceil(1681/32) K-tiles for diffusion GEMM
#define NZ 6             // diffusion GEMM k-splits (non-atomic slabs)
#define PSLAB (16L * 22L * WHP)   // 592,768 floats per z-slab
#define MKZ 4            // merge-GEMM k-splits
#define MSLAB (32L * KPOS)        // 589,824 floats per merge partial slab

typedef __attribute__((ext_vector_type(8))) __bf16 bf16x8;
typedef __attribute__((ext_vector_type(4))) float f32x4;

// ---------------- ws layout (floats) ----------------
#define WS_H2    393248L                  // 4 slabs x 836,352 = 3,345,408
#define WS_WCUM  (WS_H2 + 4L * HS)        // 564,816
#define WS_G     (WS_WCUM + 564816L)      // 141,204
#define WS_GSW   (WS_G + 141204L)         // 108,544 (bf16 x 217,088)
#define WS_W2P   (WS_GSW + 108544L + 591712L)  // pmrg 4 x 589,824 ; pacc aliases (6*592,768 fits)
#define WS_W2MB  (WS_W2P + 6193152L)      // 196,608 (bf16 x 393,216)

static __device__ __forceinline__ unsigned short f2bf(float v) {
    unsigned int b = __float_as_uint(v);
    b += 0x7FFFu + ((b >> 16) & 1u);
    return (unsigned short)(b >> 16);
}

#define LOADC(dst, ch) { const float* cc_ = cb + (long)((ch) * 32 + wv * 8) * KPOS; \
    _Pragma("unroll") for (int jj = 0; jj < 8; ++jj) dst[jj] = cc_[(long)jj * KPOS]; }

// MFMA merge GEMM: pmrg[kz][c][pos] = sum_{d in kz-split} cls_w[c,d]*conv_w[d,pos]
// A-fragments built directly from cls_w (L2-hot) — no prepack kernel.
__global__ __launch_bounds__(256) void k_mergemm(const float* __restrict__ clsw,
                                                 const float* __restrict__ convw,
                                                 float* __restrict__ pmrg) {
    __shared__ unsigned short Bs[2][64][40];
    int tid = threadIdx.x;
    int lane = tid & 63, wv = tid >> 6;
    int kg = lane >> 4, cl = lane & 15;
    int pos0 = blockIdx.x * 64;
    int kz = blockIdx.y;

    const float* cb = convw + (long)(kz * 256) * KPOS + pos0 + lane;

    f32x4 acc[2];
#pragma unroll
    for (int i = 0; i < 2; ++i) acc[i] = (f32x4){0.f, 0.f, 0.f, 0.f};

    float xr0[8], xr1[8], xrn[8];
    LOADC(xr0, 0);
    LOADC(xr1, 1);
    for (int ch = 0; ch < 8; ++ch) {
        if (ch + 2 < 8) LOADC(xrn, ch + 2);
        bf16x8 afr[2];
#pragma unroll
        for (int i = 0; i < 2; ++i) {
            int c = i * 16 + cl;
            union { unsigned short u[8]; bf16x8 v; } aw;
            if (c < NCLS) {
                const float* cw = clsw + (long)c * 1024 + kz * 256 + ch * 32 + kg * 8;
                float4 w0 = *(const float4*)cw;
                float4 w1 = *(const float4*)(cw + 4);
                aw.u[0] = f2bf(w0.x); aw.u[1] = f2bf(w0.y); aw.u[2] = f2bf(w0.z); aw.u[3] = f2bf(w0.w);
                aw.u[4] = f2bf(w1.x); aw.u[5] = f2bf(w1.y); aw.u[6] = f2bf(w1.z); aw.u[7] = f2bf(w1.w);
            } else {
#pragma unroll
                for (int j = 0; j < 8; ++j) aw.u[j] = 0;
            }
            afr[i] = aw.v;
        }
        union { unsigned short u[8]; bf16x8 v; } bw;
#pragma unroll
        for (int jj = 0; jj < 8; ++jj) bw.u[jj] = f2bf(xr0[jj]);
        int buf = ch & 1;
        *(bf16x8*)&Bs[buf][lane][wv * 8] = bw.v;
        __syncthreads();
        bf16x8 bf = *(const bf16x8*)&Bs[buf][wv * 16 + cl][kg * 8];
#pragma unroll
        for (int i = 0; i < 2; ++i)
            acc[i] = __builtin_amdgcn_mfma_f32_16x16x32_bf16(afr[i], bf, acc[i], 0, 0, 0);
#pragma unroll
        for (int jj = 0; jj < 8; ++jj) { xr0[jj] = xr1[jj]; xr1[jj] = xrn[jj]; }
    }
    float* pz = pmrg + (long)kz * MSLAB;
    int pos = pos0 + wv * 16 + cl;
#pragma unroll
    for (int i = 0; i < 2; ++i) {
#pragma unroll
        for (int rr = 0; rr < 4; ++rr) {
            int c = i * 16 + 4 * kg + rr;
            pz[(long)c * KPOS + pos] = acc[i][rr];
        }
    }
}

// fused finisher: sum merge slabs, transpose pos=(i,t)->[r][i], pack bf16 A-fragments.
__global__ void k_mfinpack(const float* __restrict__ pmrg, unsigned short* __restrict__ w2mb) {
    int gid = blockIdx.x * blockDim.x + threadIdx.x;
    if (gid >= 64 * 12 * 64) return;
    int lane = gid & 63;
    int rt = (gid >> 6) % 12;
    int kc = gid / (64 * 12);
    int cl = lane & 15, kg = lane >> 4;
    int r = rt * 16 + cl;
    unsigned short o[8];
    if (r < 189) {
        int c = r / 9, t = r - c * 9;
        const float* base = pmrg + (long)c * KPOS + t;
#pragma unroll
        for (int j = 0; j < 8; ++j) {
            int i = kc * 32 + kg * 8 + j;
            long pos = (long)i * 9;
            float s = 0.f;
#pragma unroll
            for (int kz = 0; kz < MKZ; ++kz) s += base[(long)kz * MSLAB + pos];
            o[j] = f2bf(s);
        }
    } else {
#pragma unroll
        for (int j = 0; j < 8; ++j) o[j] = 0;
    }
    unsigned short* p = w2mb + (long)gid * 8;
#pragma unroll
    for (int j = 0; j < 8; ++j) p[j] = o[j];
}

#define LOADX(dst, ch) { const float* xc_ = xb + (long)((ch) * 32 + wv * 8) * NSRC; \
    _Pragma("unroll") for (int jj = 0; jj < 8; ++jj) dst[jj] = nok ? xc_[(long)jj * NSRC] : 0.f; }

// MFMA main GEMM: Hp[ks][b][r][n] = sum_{k in ks-split} w2m[r][k] * x[b][k][n]
__global__ __launch_bounds__(256) void k_gemmm(const unsigned short* __restrict__ w2mb,
                                               const float* __restrict__ x,
                                               float* __restrict__ Hp) {
    __shared__ unsigned short Bs[2][64][40];
    int tid = threadIdx.x;
    int lane = tid & 63, wv = tid >> 6;
    int kg = lane >> 4, cl = lane & 15;
    int n0 = blockIdx.x * 64;
    int b  = blockIdx.y;
    int ks = blockIdx.z;

    const float* xb = x + ((long)b * CIN + ks * 512) * NSRC + n0 + lane;
    bool nok = (n0 + lane) < NSRC;

    f32x4 acc[3][4];
#pragma unroll
    for (int i = 0; i < 3; ++i)
#pragma unroll
        for (int ct = 0; ct < 4; ++ct) acc[i][ct] = (f32x4){0.f, 0.f, 0.f, 0.f};

    float xr0[8], xr1[8], xrn[8];
    LOADX(xr0, 0);
    LOADX(xr1, 1);
    for (int ch = 0; ch < 16; ++ch) {
        if (ch + 2 < 16) LOADX(xrn, ch + 2);
        bf16x8 afr[3];
        const unsigned short* wb = w2mb + (((long)(ks * 16 + ch) * 12 + wv * 3) * 64 + lane) * 8;
#pragma unroll
        for (int i = 0; i < 3; ++i) afr[i] = *(const bf16x8*)(wb + (long)i * 64 * 8);
        union { unsigned short u[8]; bf16x8 v; } bw;
#pragma unroll
        for (int jj = 0; jj < 8; ++jj) bw.u[jj] = f2bf(xr0[jj]);
        int buf = ch & 1;
        *(bf16x8*)&Bs[buf][lane][wv * 8] = bw.v;
        __syncthreads();
#pragma unroll
        for (int ct = 0; ct < 4; ++ct) {
            bf16x8 bf = *(const bf16x8*)&Bs[buf][ct * 16 + cl][kg * 8];
#pragma unroll
            for (int i = 0; i < 3; ++i)
                acc[i][ct] = __builtin_amdgcn_mfma_f32_16x16x32_bf16(afr[i], bf, acc[i][ct], 0, 0, 0);
        }
#pragma unroll
        for (int jj = 0; jj < 8; ++jj) { xr0[jj] = xr1[jj]; xr1[jj] = xrn[jj]; }
    }
    float* Hb = Hp + (long)ks * HS + (long)b * MR * NSRC;
#pragma unroll
    for (int i = 0; i < 3; ++i) {
        int r0 = (wv * 3 + i) * 16 + 4 * kg;
#pragma unroll
        for (int ct = 0; ct < 4; ++ct) {
            int n = n0 + ct * 16 + cl;
            if (n < NSRC) {
#pragma unroll
                for (int rr = 0; rr < 4; ++rr)
                    Hb[(long)(r0 + rr) * NSRC + n] = acc[i][ct][rr];
            }
        }
    }
}

// g[b][c][m] = sum_t ok(m,t) * Bilinear41->33(H[b][c*9+t]); H = sum of 4 slabs
__global__ void k_combine(const float* __restrict__ Hp, float* __restrict__ g) {
    int gid = blockIdx.x * blockDim.x + threadIdx.x;
    if (gid >= BS * NCLS * WH) return;
    int m = gid % WH;
    int t_ = gid / WH;
    int c = t_ % NCLS;
    int b = t_ / NCLS;
    int yy = m / 41, xx = m - yy * 41;
    const float S = 33.0f / 41.0f;
    int y0a[3], y1a[3], x0a[3], x1a[3];
    float wya[3], wxa[3];
    bool oky[3], okx[3];
#pragma unroll
    for (int o = 0; o < 3; ++o) {
        int yp = yy + 6 * o - 6;
        oky[o] = (yp >= 0 && yp < 41);
        float sy = (yp + 0.5f) * S - 0.5f;
        float fy = floorf(sy);
        wya[o] = sy - fy;
        int y0 = (int)fy;
        y0a[o] = min(max(y0, 0), 32);
        y1a[o] = min(max(y0 + 1, 0), 32);
        int xp = xx + 6 * o - 6;
        okx[o] = (xp >= 0 && xp < 41);
        float sx = (xp + 0.5f) * S - 0.5f;
        float fx = floorf(sx);
        wxa[o] = sx - fx;
        int x0 = (int)fx;
        x0a[o] = min(max(x0, 0), 32);
        x1a[o] = min(max(x0 + 1, 0), 32);
    }
    float acc = 0.f;
    const float* Hb = Hp + ((long)b * MR + c * 9) * NSRC;
#pragma unroll
    for (int ty = 0; ty < 3; ++ty) {
#pragma unroll
        for (int tx = 0; tx < 3; ++tx) {
            if (oky[ty] && okx[tx]) {
                const float* hr = Hb + (ty * 3 + tx) * NSRC;
                int i00 = y0a[ty] * 33 + x0a[tx], i01 = y0a[ty] * 33 + x1a[tx];
                int i10 = y1a[ty] * 33 + x0a[tx], i11 = y1a[ty] * 33 + x1a[tx];
                float v00 = 0.f, v01 = 0.f, v10 = 0.f, v11 = 0.f;
#pragma unroll
                for (int s = 0; s < 4; ++s) {
                    const float* h2 = hr + (long)s * HS;
                    v00 += h2[i00]; v01 += h2[i01]; v10 += h2[i10]; v11 += h2[i11];
                }
                float wy = wya[ty], wx = wxa[tx];
                float v0 = v00 + wx * (v01 - v00);
                float v1 = v10 + wx * (v11 - v10);
                acc += v0 + wy * (v1 - v0);
            }
        }
    }
    g[gid] = acc;
}

// pack g^T (bf16) into MFMA B-fragment order, plus ones column (col 21).
__global__ void k_gpack(const float* __restrict__ g, unsigned short* __restrict__ Gsw) {
    int gid = blockIdx.x * blockDim.x + threadIdx.x;
    if (gid >= BS * NT * 2 * 64) return;
    int lane = gid & 63;
    int t = gid >> 6;
    int ct = t & 1; t >>= 1;
    int nt = t % NT;
    int b  = t / NT;
    int col = ct * 16 + (lane & 15);
    int nb = nt * 32 + (lane >> 4) * 8;
    unsigned short out[8];
#pragma unroll
    for (int j = 0; j < 8; ++j) {
        int n = nb + j;
        unsigned short v = 0;
        if (n < WH) {
            if (col < NCLS) v = f2bf(g[((long)b * NCLS + col) * WH + n]);
            else if (col == NCLS) v = 0x3F80;
        }
        out[j] = v;
    }
    unsigned short* p = Gsw + (long)gid * 8;
#pragma unroll
    for (int j = 0; j < 8; ++j) p[j] = out[j];
}

// fused mask-GEMM with LDS-coalesced diffW staging
__global__ __launch_bounds__(256) void k_dgemm(const float* __restrict__ diffW,
                                               const unsigned short* __restrict__ Gsw,
                                               const float* __restrict__ msc,
                                               float* __restrict__ pacc) {
    __shared__ float Ds[2][64][36];
    int tid  = threadIdx.x;
    int lane = tid & 63, wv = tid >> 6;
    int b = blockIdx.y, z = blockIdx.z;
    int m0 = blockIdx.x * 64;
    int m0w = m0 + wv * 16;
    int kg = lane >> 4;
    int cl = lane & 15;
    float thr[4];
#pragma unroll
    for (int it = 0; it < 4; ++it) thr[it] = msc[it];
    int nt0 = (z * NT) / NZ;
    int nt1 = ((z + 1) * NT) / NZ;

    int scol = tid & 31;
    int srow = tid >> 5;
    long rb[8];
#pragma unroll
    for (int p = 0; p < 8; ++p) {
        int mr = m0 + srow + 8 * p; if (mr > WH - 1) mr = WH - 1;
        rb[p] = ((long)b * WH + mr) * WH;
    }
    const unsigned short* gb = Gsw + (long)b * NT * 2 * 64 * 8;

    f32x4 accv[4][2];
#pragma unroll
    for (int it = 0; it < 4; ++it)
#pragma unroll
        for (int ct = 0; ct < 2; ++ct) accv[it][ct] = (f32x4){0.f, 0.f, 0.f, 0.f};

    for (int nt = nt0; nt < nt1; ++nt) {
        int nb = nt * 32;
        int buf = nt & 1;
        int ncol = nb + scol;
        if (ncol <= WH - 1) {
#pragma unroll
            for (int p = 0; p < 8; ++p) Ds[buf][srow + 8 * p][scol] = diffW[rb[p] + ncol];
        } else {
#pragma unroll
            for (int p = 0; p < 8; ++p) Ds[buf][srow + 8 * p][scol] = -1e30f;
        }
        __syncthreads();

        float dw[8];
        const float* dsr = &Ds[buf][wv * 16 + cl][kg * 8];
#pragma unroll
        for (int j = 0; j < 8; ++j) dw[j] = dsr[j];

        union { unsigned short u[8]; bf16x8 v; } af[4];
#pragma unroll
        for (int it = 0; it < 4; ++it)
#pragma unroll
            for (int j = 0; j < 8; ++j)
                af[it].u[j] = (dw[j] > thr[it]) ? (unsigned short)0x3F80 : (unsigned short)0;

        const unsigned short* gp = gb + ((long)nt * 2 * 64 + lane) * 8;
        bf16x8 b0 = *(const bf16x8*)gp;
        bf16x8 b1 = *(const bf16x8*)(gp + 64 * 8);
#pragma unroll
        for (int it = 0; it < 4; ++it) {
            accv[it][0] = __builtin_amdgcn_mfma_f32_16x16x32_bf16(af[it].v, b0, accv[it][0], 0, 0, 0);
            accv[it][1] = __builtin_amdgcn_mfma_f32_16x16x32_bf16(af[it].v, b1, accv[it][1], 0, 0, 0);
        }
    }
    float* pz = pacc + (long)z * PSLAB;
    int mbase = m0w + 4 * kg;
#pragma unroll
    for (int it = 0; it < 4; ++it) {
#pragma unroll
        for (int ct = 0; ct < 2; ++ct) {
            int c = ct * 16 + cl;
            if (c < 22) {
                float* dst = pz + ((long)(b * 4 + it) * 22 + c) * WHP + mbase;
                if (mbase + 3 < WH) {
                    *(f32x4*)dst = accv[it][ct];
                } else {
#pragma unroll
                    for (int r = 0; r < 4; ++r)
                        if (mbase + r < WH) dst[r] = accv[it][ct][r];
                }
            }
        }
    }
}

// wcum_raw[b][it][c][m] = (sum_z pacc[z][c][m]) / (sum_z pacc[z][21][m])   (Kc added in k_mask)
__global__ void k_dfin(const float* __restrict__ pacc, float* __restrict__ wcum) {
    int gid = blockIdx.x * blockDim.x + threadIdx.x;
    if (gid >= BS * 4 * NCLS * WH) return;
    int m = gid % WH;
    int t = gid / WH;
    int c = t % NCLS; t /= NCLS;
    int it = t & 3;
    int b = t >> 2;
    long rowc = ((long)(b * 4 + it) * 22 + c) * WHP + m;
    long rown = ((long)(b * 4 + it) * 22 + NCLS) * WHP + m;
    float num = 0.f, cnt = 0.f;
#pragma unroll
    for (int z = 0; z < NZ; ++z) {
        num += pacc[(long)z * PSLAB + rowc];
        cnt += pacc[(long)z * PSLAB + rown];
    }
    wcum[(((long)b * 4 + it) * NCLS + c) * WH + m] = num / cnt;
}

// per-(b,m): add Kc (computed per block), scale-softmax mask, fused logits, two 21-way
// softmaxes. grid 106 x 64 (1 wave per block)
__global__ __launch_bounds__(64) void k_mask(const float* __restrict__ wcum,
                                             const float* __restrict__ smw,
                                             const float* __restrict__ clsw,
                                             const float* __restrict__ convb,
                                             const float* __restrict__ clsb,
                                             float* __restrict__ out_wc2,
                                             float* __restrict__ out_wei,
                                             float* __restrict__ out_mask) {
    __shared__ float KcS[NCLS];
    int lane = threadIdx.x;
    for (int c = 0; c < NCLS; ++c) {
        float s = 0.f;
        for (int d = lane; d < 1024; d += 64) s += clsw[c * 1024 + d] * convb[d];
#pragma unroll
        for (int o = 1; o < 64; o <<= 1) s += __shfl_xor(s, o, 64);
        if (lane == 0) KcS[c] = s + clsb[c];
    }
    __syncthreads();

    int gid = blockIdx.x * 64 + lane;
    if (gid >= BS * WH) return;
    int b = gid / WH, m = gid - b * WH;
    const float* base = wcum + (long)b * 4 * NCLS * WH + m;

    float fused[21];
#pragma unroll
    for (int c = 0; c < NCLS; ++c) {
        float kc = KcS[c];
        float sc = smw[c];
        float L0 = base[(0 * NCLS + c) * WH] + kc;
        float L1 = base[(1 * NCLS + c) * WH] + kc;
        float L2 = base[(2 * NCLS + c) * WH] + kc;
        float L3 = base[(3 * NCLS + c) * WH] + kc;
        float a0 = sc * L0, a1 = sc * L1, a2 = sc * L2, a3 = sc * L3;
        float mx = fmaxf(fmaxf(a0, a1), fmaxf(a2, a3));
        float e0 = __expf(a0 - mx), e1 = __expf(a1 - mx), e2 = __expf(a2 - mx), e3 = __expf(a3 - mx);
        float inv = 1.0f / (e0 + e1 + e2 + e3);
        e0 *= inv; e1 *= inv; e2 *= inv; e3 *= inv;
        out_mask[((long)(b * 4 + 0) * NCLS + c) * WH + m] = e0;
        out_mask[((long)(b * 4 + 1) * NCLS + c) * WH + m] = e1;
        out_mask[((long)(b * 4 + 2) * NCLS + c) * WH + m] = e2;
        out_mask[((long)(b * 4 + 3) * NCLS + c) * WH + m] = e3;
        fused[c] = L0 * e0 + L1 * e1 + L2 * e2 + L3 * e3;
    }
    float mx = -1e30f;
#pragma unroll
    for (int c = 0; c < NCLS; ++c) mx = fmaxf(mx, fused[c]);
    float s = 0.f;
    float e[21];
#pragma unroll
    for (int c = 0; c < NCLS; ++c) { e[c] = __expf(fused[c] - mx); s += e[c]; }
    float inv = 1.0f / s;
#pragma unroll
    for (int c = 0; c < NCLS; ++c) {
        e[c] *= inv;
        out_wc2[((long)b * NCLS + c) * WH + m] = e[c];
    }
    mx = -1e30f;
#pragma unroll
    for (int c = 0; c < NCLS; ++c) mx = fmaxf(mx, e[c]);
    s = 0.f;
    float e2a[21];
#pragma unroll
    for (int c = 0; c < NCLS; ++c) { e2a[c] = __expf(e[c] - mx); s += e2a[c]; }
    inv = 1.0f / s;
#pragma unroll
    for (int c = 0; c < NCLS; ++c) out_wei[((long)b * NCLS + c) * WH + m] = e2a[c] * inv;
}

// per-(b,c): softmax-pool over m with g, sigmoid; Kc computed inline. grid (21,4) x 256
__global__ void k_pool(const float* __restrict__ wei, const float* __restrict__ g,
                       const float* __restrict__ poolw, const float* __restrict__ clsw,
                       const float* __restrict__ convb, const float* __restrict__ clsb,
                       float* __restrict__ prob) {
    int c = blockIdx.x, b = blockIdx.y;
    const float* wr = wei + ((long)b * NCLS + c) * WH;
    const float* gr = g + ((long)b * NCLS + c) * WH;
    float E = __expf(poolw[c]);
    __shared__ float red[256];
    float mx = -1e30f;
    for (int m = threadIdx.x; m < WH; m += 256) mx = fmaxf(mx, wr[m] * E);
    red[threadIdx.x] = mx; __syncthreads();
    for (int o = 128; o > 0; o >>= 1) {
        if (threadIdx.x < o) red[threadIdx.x] = fmaxf(red[threadIdx.x], red[threadIdx.x + o]);
        __syncthreads();
    }
    mx = red[0]; __syncthreads();
    float se = 0.f, sg = 0.f, kcp = 0.f;
    for (int m = threadIdx.x; m < WH; m += 256) {
        float ev = __expf(wr[m] * E - mx);
        se += ev; sg += ev * gr[m];
    }
    for (int d = threadIdx.x; d < 1024; d += 256) kcp += clsw[c * 1024 + d] * convb[d];
    red[threadIdx.x] = se; __syncthreads();
    for (int o = 128; o > 0; o >>= 1) {
        if (threadIdx.x < o) red[threadIdx.x] += red[threadIdx.x + o];
        __syncthreads();
    }
    se = red[0]; __syncthreads();
    red[threadIdx.x] = sg; __syncthreads();
    for (int o = 128; o > 0; o >>= 1) {
        if (threadIdx.x < o) red[threadIdx.x] += red[threadIdx.x + o];
        __syncthreads();
    }
    sg = red[0]; __syncthreads();
    red[threadIdx.x] = kcp; __syncthreads();
    for (int o = 128; o > 0; o >>= 1) {
        if (threadIdx.x < o) red[threadIdx.x] += red[threadIdx.x + o];
        __syncthreads();
    }
    kcp = red[0];
    if (threadIdx.x == 0) {
        float out = sg / se + kcp + clsb[c];
        prob[b * NCLS + c] = 1.0f / (1.0f + __expf(-out));
    }
}

// ---------------- launcher ----------------
extern "C" void kernel_launch(void* const* d_in, const int* in_sizes, int n_in,
                              void* d_out, int out_size, void* d_ws, size_t ws_size,
                              hipStream_t stream) {
    const float* x      = (const float*)d_in[0];
    const float* diffW  = (const float*)d_in[1];
    const float* conv_w = (const float*)d_in[2];
    const float* conv_b = (const float*)d_in[3];
    const float* cls_w  = (const float*)d_in[4];
    const float* cls_b  = (const float*)d_in[5];
    const float* smw    = (const float*)d_in[6];
    const float* poolw  = (const float*)d_in[7];
    const float* msc    = (const float*)d_in[8];

    float* ws   = (float*)d_ws;
    float* Hp   = ws + WS_H2;
    float* wcum = ws + WS_WCUM;
    float* g    = ws + WS_G;
    unsigned short* Gsw  = (unsigned short*)(ws + WS_GSW);
    float* pmrg = ws + WS_W2P;
    float* pacc = ws + WS_W2P;            // aliases pmrg (dead once w2mb packed)
    unsigned short* w2mb = (unsigned short*)(ws + WS_W2MB);

    float* out  = (float*)d_out;
    float* o_prob = out;                       // [4][1][21]
    float* o_wc2  = out + 84;                  // [4][21][1681]
    float* o_wei  = out + 84 + 141204;         // [4][21][1681]
    float* o_mask = out + 84 + 141204 + 141204;// [4][4][21][1681]

    k_mergemm<<<dim3(KPOS / 64, MKZ), 256, 0, stream>>>(cls_w, conv_w, pmrg);
    k_mfinpack<<<(64 * 12 * 64 + 255) / 256, 256, 0, stream>>>(pmrg, w2mb);
    k_gemmm<<<dim3(18, BS, 4), 256, 0, stream>>>(w2mb, x, Hp);
    k_combine<<<(BS * NCLS * WH + 255) / 256, 256, 0, stream>>>(Hp, g);
    k_gpack<<<(BS * NT * 2 * 64 + 255) / 256, 256, 0, stream>>>(g, Gsw);
    k_dgemm<<<dim3(27, BS, NZ), 256, 0, stream>>>(diffW, Gsw, msc, pacc);
    k_dfin<<<(BS * 4 * NCLS * WH + 255) / 256, 256, 0, stream>>>(pacc, wcum);
    k_mask<<<(BS * WH + 63) / 64, 64, 0, stream>>>(wcum, smw, cls_w, conv_b, cls_b,
                                                   o_wc2, o_wei, o_mask);
    k_pool<<<dim3(NCLS, BS), 256, 0, stream>>>(o_wei, g, poolw, cls_w, conv_b, cls_b, o_prob);
}

// Round 17
// 102.549 us; speedup vs baseline: 1.7796x; 1.7796x over previous
//
#include <hip/hip_runtime.h>
#include <hip/hip_bf16.h>
#include <math.h>

#define NCLS 21
#define WH 1681          // 41*41
#define WHP 1684         // padded row stride for pacc (16B-aligned float4 stores)
#define BS 4
#define CIN 2048
#define NSRC 1089        // 33*33
#define KPOS 18432       // 2048*9
#define MR 192           // 21*9=189 padded to 192
#define HS 836352        // one k-split slab of Hp
#define NT 53            // ceil(1681/32) K-tiles for diffusion GEMM
#define NZ 6             // diffusion GEMM k-splits (non-atomic slabs)
#define PSLAB (16L * 22L * WHP)   // 592,768 floats per z-slab
#define MKZ 4            // merge-GEMM k-splits
#define MSLAB (32L * KPOS)        // 589,824 floats per merge partial slab

typedef __attribute__((ext_vector_type(8))) __bf16 bf16x8;
typedef __attribute__((ext_vector_type(4))) float f32x4;

// ---------------- ws layout (floats) ----------------
#define WS_KC    393216L                  // 32
#define WS_H2    393248L                  // 4 slabs x 836,352 = 3,345,408
#define WS_WCUM  (WS_H2 + 4L * HS)        // 564,816
#define WS_G     (WS_WCUM + 564816L)      // 141,204
#define WS_GSW   (WS_G + 141204L)         // 108,544 (bf16 x 217,088)
#define WS_W2P   (WS_GSW + 108544L + 591712L)  // pmrg 4 x 589,824 ; pacc aliases (6*592,768 fits)
#define WS_W2MB  (WS_W2P + 6193152L)      // 196,608 (bf16 x 393,216)

static __device__ __forceinline__ unsigned short f2bf(float v) {
    unsigned int b = __float_as_uint(v);
    b += 0x7FFFu + ((b >> 16) & 1u);
    return (unsigned short)(b >> 16);
}

// Kc[c] = sum_d cls_w[c,d]*conv_b[d] + cls_b[c]  (grid 21 x 256)
__global__ void k_const(const float* __restrict__ clsw, const float* __restrict__ convb,
                        const float* __restrict__ clsb, float* __restrict__ Kc) {
    __shared__ float red[256];
    int c = blockIdx.x;
    float s = 0.f;
    for (int d = threadIdx.x; d < 1024; d += 256) s += clsw[c * 1024 + d] * convb[d];
    red[threadIdx.x] = s; __syncthreads();
    for (int o = 128; o > 0; o >>= 1) {
        if (threadIdx.x < o) red[threadIdx.x] += red[threadIdx.x + o];
        __syncthreads();
    }
    if (threadIdx.x == 0) Kc[c] = red[0] + clsb[c];
}

#define LOADC(dst, ch) { const float* cc_ = cb + (long)((ch) * 32 + wv * 8) * KPOS; \
    _Pragma("unroll") for (int jj = 0; jj < 8; ++jj) dst[jj] = cc_[(long)jj * KPOS]; }

// MFMA merge GEMM: pmrg[kz][c][pos] = sum_{d in kz-split} cls_w[c,d]*conv_w[d,pos]
// A-fragments built directly from cls_w (L2-hot) — no prepack kernel.
__global__ __launch_bounds__(256) void k_mergemm(const float* __restrict__ clsw,
                                                 const float* __restrict__ convw,
                                                 float* __restrict__ pmrg) {
    __shared__ unsigned short Bs[2][64][40];
    int tid = threadIdx.x;
    int lane = tid & 63, wv = tid >> 6;
    int kg = lane >> 4, cl = lane & 15;
    int pos0 = blockIdx.x * 64;
    int kz = blockIdx.y;

    const float* cb = convw + (long)(kz * 256) * KPOS + pos0 + lane;

    f32x4 acc[2];
#pragma unroll
    for (int i = 0; i < 2; ++i) acc[i] = (f32x4){0.f, 0.f, 0.f, 0.f};

    float xr0[8], xr1[8], xrn[8];
    LOADC(xr0, 0);
    LOADC(xr1, 1);
    for (int ch = 0; ch < 8; ++ch) {
        if (ch + 2 < 8) LOADC(xrn, ch + 2);
        bf16x8 afr[2];
#pragma unroll
        for (int i = 0; i < 2; ++i) {
            int c = i * 16 + cl;
            union { unsigned short u[8]; bf16x8 v; } aw;
            if (c < NCLS) {
                const float* cw = clsw + (long)c * 1024 + kz * 256 + ch * 32 + kg * 8;
                float4 w0 = *(const float4*)cw;
                float4 w1 = *(const float4*)(cw + 4);
                aw.u[0] = f2bf(w0.x); aw.u[1] = f2bf(w0.y); aw.u[2] = f2bf(w0.z); aw.u[3] = f2bf(w0.w);
                aw.u[4] = f2bf(w1.x); aw.u[5] = f2bf(w1.y); aw.u[6] = f2bf(w1.z); aw.u[7] = f2bf(w1.w);
            } else {
#pragma unroll
                for (int j = 0; j < 8; ++j) aw.u[j] = 0;
            }
            afr[i] = aw.v;
        }
        union { unsigned short u[8]; bf16x8 v; } bw;
#pragma unroll
        for (int jj = 0; jj < 8; ++jj) bw.u[jj] = f2bf(xr0[jj]);
        int buf = ch & 1;
        *(bf16x8*)&Bs[buf][lane][wv * 8] = bw.v;
        __syncthreads();
        bf16x8 bf = *(const bf16x8*)&Bs[buf][wv * 16 + cl][kg * 8];
#pragma unroll
        for (int i = 0; i < 2; ++i)
            acc[i] = __builtin_amdgcn_mfma_f32_16x16x32_bf16(afr[i], bf, acc[i], 0, 0, 0);
#pragma unroll
        for (int jj = 0; jj < 8; ++jj) { xr0[jj] = xr1[jj]; xr1[jj] = xrn[jj]; }
    }
    float* pz = pmrg + (long)kz * MSLAB;
    int pos = pos0 + wv * 16 + cl;
#pragma unroll
    for (int i = 0; i < 2; ++i) {
#pragma unroll
        for (int rr = 0; rr < 4; ++rr) {
            int c = i * 16 + 4 * kg + rr;
            pz[(long)c * KPOS + pos] = acc[i][rr];
        }
    }
}

// fused finisher: sum merge slabs, transpose pos=(i,t)->[r][i], pack bf16 A-fragments.
__global__ void k_mfinpack(const float* __restrict__ pmrg, unsigned short* __restrict__ w2mb) {
    int gid = blockIdx.x * blockDim.x + threadIdx.x;
    if (gid >= 64 * 12 * 64) return;
    int lane = gid & 63;
    int rt = (gid >> 6) % 12;
    int kc = gid / (64 * 12);
    int cl = lane & 15, kg = lane >> 4;
    int r = rt * 16 + cl;
    unsigned short o[8];
    if (r < 189) {
        int c = r / 9, t = r - c * 9;
        const float* base = pmrg + (long)c * KPOS + t;
#pragma unroll
        for (int j = 0; j < 8; ++j) {
            int i = kc * 32 + kg * 8 + j;
            long pos = (long)i * 9;
            float s = 0.f;
#pragma unroll
            for (int kz = 0; kz < MKZ; ++kz) s += base[(long)kz * MSLAB + pos];
            o[j] = f2bf(s);
        }
    } else {
#pragma unroll
        for (int j = 0; j < 8; ++j) o[j] = 0;
    }
    unsigned short* p = w2mb + (long)gid * 8;
#pragma unroll
    for (int j = 0; j < 8; ++j) p[j] = o[j];
}

#define LOADX(dst, ch) { const float* xc_ = xb + (long)((ch) * 32 + wv * 8) * NSRC; \
    _Pragma("unroll") for (int jj = 0; jj < 8; ++jj) dst[jj] = nok ? xc_[(long)jj * NSRC] : 0.f; }

// MFMA main GEMM: Hp[ks][b][r][n] = sum_{k in ks-split} w2m[r][k] * x[b][k][n]
__global__ __launch_bounds__(256) void k_gemmm(const unsigned short* __restrict__ w2mb,
                                               const float* __restrict__ x,
                                               float* __restrict__ Hp) {
    __shared__ unsigned short Bs[2][64][40];
    int tid = threadIdx.x;
    int lane = tid & 63, wv = tid >> 6;
    int kg = lane >> 4, cl = lane & 15;
    int n0 = blockIdx.x * 64;
    int b  = blockIdx.y;
    int ks = blockIdx.z;

    const float* xb = x + ((long)b * CIN + ks * 512) * NSRC + n0 + lane;
    bool nok = (n0 + lane) < NSRC;

    f32x4 acc[3][4];
#pragma unroll
    for (int i = 0; i < 3; ++i)
#pragma unroll
        for (int ct = 0; ct < 4; ++ct) acc[i][ct] = (f32x4){0.f, 0.f, 0.f, 0.f};

    float xr0[8], xr1[8], xrn[8];
    LOADX(xr0, 0);
    LOADX(xr1, 1);
    for (int ch = 0; ch < 16; ++ch) {
        if (ch + 2 < 16) LOADX(xrn, ch + 2);
        bf16x8 afr[3];
        const unsigned short* wb = w2mb + (((long)(ks * 16 + ch) * 12 + wv * 3) * 64 + lane) * 8;
#pragma unroll
        for (int i = 0; i < 3; ++i) afr[i] = *(const bf16x8*)(wb + (long)i * 64 * 8);
        union { unsigned short u[8]; bf16x8 v; } bw;
#pragma unroll
        for (int jj = 0; jj < 8; ++jj) bw.u[jj] = f2bf(xr0[jj]);
        int buf = ch & 1;
        *(bf16x8*)&Bs[buf][lane][wv * 8] = bw.v;
        __syncthreads();
#pragma unroll
        for (int ct = 0; ct < 4; ++ct) {
            bf16x8 bf = *(const bf16x8*)&Bs[buf][ct * 16 + cl][kg * 8];
#pragma unroll
            for (int i = 0; i < 3; ++i)
                acc[i][ct] = __builtin_amdgcn_mfma_f32_16x16x32_bf16(afr[i], bf, acc[i][ct], 0, 0, 0);
        }
#pragma unroll
        for (int jj = 0; jj < 8; ++jj) { xr0[jj] = xr1[jj]; xr1[jj] = xrn[jj]; }
    }
    float* Hb = Hp + (long)ks * HS + (long)b * MR * NSRC;
#pragma unroll
    for (int i = 0; i < 3; ++i) {
        int r0 = (wv * 3 + i) * 16 + 4 * kg;
#pragma unroll
        for (int ct = 0; ct < 4; ++ct) {
            int n = n0 + ct * 16 + cl;
            if (n < NSRC) {
#pragma unroll
                for (int rr = 0; rr < 4; ++rr)
                    Hb[(long)(r0 + rr) * NSRC + n] = acc[i][ct][rr];
            }
        }
    }
}

// g[b][c][m] = sum_t ok(m,t) * Bilinear41->33(H[b][c*9+t]); H = sum of 4 slabs
__global__ void k_combine(const float* __restrict__ Hp, float* __restrict__ g) {
    int gid = blockIdx.x * blockDim.x + threadIdx.x;
    if (gid >= BS * NCLS * WH) return;
    int m = gid % WH;
    int t_ = gid / WH;
    int c = t_ % NCLS;
    int b = t_ / NCLS;
    int yy = m / 41, xx = m - yy * 41;
    const float S = 33.0f / 41.0f;
    int y0a[3], y1a[3], x0a[3], x1a[3];
    float wya[3], wxa[3];
    bool oky[3], okx[3];
#pragma unroll
    for (int o = 0; o < 3; ++o) {
        int yp = yy + 6 * o - 6;
        oky[o] = (yp >= 0 && yp < 41);
        float sy = (yp + 0.5f) * S - 0.5f;
        float fy = floorf(sy);
        wya[o] = sy - fy;
        int y0 = (int)fy;
        y0a[o] = min(max(y0, 0), 32);
        y1a[o] = min(max(y0 + 1, 0), 32);
        int xp = xx + 6 * o - 6;
        okx[o] = (xp >= 0 && xp < 41);
        float sx = (xp + 0.5f) * S - 0.5f;
        float fx = floorf(sx);
        wxa[o] = sx - fx;
        int x0 = (int)fx;
        x0a[o] = min(max(x0, 0), 32);
        x1a[o] = min(max(x0 + 1, 0), 32);
    }
    float acc = 0.f;
    const float* Hb = Hp + ((long)b * MR + c * 9) * NSRC;
#pragma unroll
    for (int ty = 0; ty < 3; ++ty) {
#pragma unroll
        for (int tx = 0; tx < 3; ++tx) {
            if (oky[ty] && okx[tx]) {
                const float* hr = Hb + (ty * 3 + tx) * NSRC;
                int i00 = y0a[ty] * 33 + x0a[tx], i01 = y0a[ty] * 33 + x1a[tx];
                int i10 = y1a[ty] * 33 + x0a[tx], i11 = y1a[ty] * 33 + x1a[tx];
                float v00 = 0.f, v01 = 0.f, v10 = 0.f, v11 = 0.f;
#pragma unroll
                for (int s = 0; s < 4; ++s) {
                    const float* h2 = hr + (long)s * HS;
                    v00 += h2[i00]; v01 += h2[i01]; v10 += h2[i10]; v11 += h2[i11];
                }
                float wy = wya[ty], wx = wxa[tx];
                float v0 = v00 + wx * (v01 - v00);
                float v1 = v10 + wx * (v11 - v10);
                acc += v0 + wy * (v1 - v0);
            }
        }
    }
    g[gid] = acc;
}

// pack g^T (bf16) into MFMA B-fragment order, plus ones column (col 21).
__global__ void k_gpack(const float* __restrict__ g, unsigned short* __restrict__ Gsw) {
    int gid = blockIdx.x * blockDim.x + threadIdx.x;
    if (gid >= BS * NT * 2 * 64) return;
    int lane = gid & 63;
    int t = gid >> 6;
    int ct = t & 1; t >>= 1;
    int nt = t % NT;
    int b  = t / NT;
    int col = ct * 16 + (lane & 15);
    int nb = nt * 32 + (lane >> 4) * 8;
    unsigned short out[8];
#pragma unroll
    for (int j = 0; j < 8; ++j) {
        int n = nb + j;
        unsigned short v = 0;
        if (n < WH) {
            if (col < NCLS) v = f2bf(g[((long)b * NCLS + col) * WH + n]);
            else if (col == NCLS) v = 0x3F80;
        }
        out[j] = v;
    }
    unsigned short* p = Gsw + (long)gid * 8;
#pragma unroll
    for (int j = 0; j < 8; ++j) p[j] = out[j];
}

// fused mask-GEMM with LDS-coalesced diffW staging
__global__ __launch_bounds__(256) void k_dgemm(const float* __restrict__ diffW,
                                               const unsigned short* __restrict__ Gsw,
                                               const float* __restrict__ msc,
                                               float* __restrict__ pacc) {
    __shared__ float Ds[2][64][36];
    int tid  = threadIdx.x;
    int lane = tid & 63, wv = tid >> 6;
    int b = blockIdx.y, z = blockIdx.z;
    int m0 = blockIdx.x * 64;
    int m0w = m0 + wv * 16;
    int kg = lane >> 4;
    int cl = lane & 15;
    float thr[4];
#pragma unroll
    for (int it = 0; it < 4; ++it) thr[it] = msc[it];
    int nt0 = (z * NT) / NZ;
    int nt1 = ((z + 1) * NT) / NZ;

    int scol = tid & 31;
    int srow = tid >> 5;
    long rb[8];
#pragma unroll
    for (int p = 0; p < 8; ++p) {
        int mr = m0 + srow + 8 * p; if (mr > WH - 1) mr = WH - 1;
        rb[p] = ((long)b * WH + mr) * WH;
    }
    const unsigned short* gb = Gsw + (long)b * NT * 2 * 64 * 8;

    f32x4 accv[4][2];
#pragma unroll
    for (int it = 0; it < 4; ++it)
#pragma unroll
        for (int ct = 0; ct < 2; ++ct) accv[it][ct] = (f32x4){0.f, 0.f, 0.f, 0.f};

    for (int nt = nt0; nt < nt1; ++nt) {
        int nb = nt * 32;
        int buf = nt & 1;
        int ncol = nb + scol;
        if (ncol <= WH - 1) {
#pragma unroll
            for (int p = 0; p < 8; ++p) Ds[buf][srow + 8 * p][scol] = diffW[rb[p] + ncol];
        } else {
#pragma unroll
            for (int p = 0; p < 8; ++p) Ds[buf][srow + 8 * p][scol] = -1e30f;
        }
        __syncthreads();

        float dw[8];
        const float* dsr = &Ds[buf][wv * 16 + cl][kg * 8];
#pragma unroll
        for (int j = 0; j < 8; ++j) dw[j] = dsr[j];

        union { unsigned short u[8]; bf16x8 v; } af[4];
#pragma unroll
        for (int it = 0; it < 4; ++it)
#pragma unroll
            for (int j = 0; j < 8; ++j)
                af[it].u[j] = (dw[j] > thr[it]) ? (unsigned short)0x3F80 : (unsigned short)0;

        const unsigned short* gp = gb + ((long)nt * 2 * 64 + lane) * 8;
        bf16x8 b0 = *(const bf16x8*)gp;
        bf16x8 b1 = *(const bf16x8*)(gp + 64 * 8);
#pragma unroll
        for (int it = 0; it < 4; ++it) {
            accv[it][0] = __builtin_amdgcn_mfma_f32_16x16x32_bf16(af[it].v, b0, accv[it][0], 0, 0, 0);
            accv[it][1] = __builtin_amdgcn_mfma_f32_16x16x32_bf16(af[it].v, b1, accv[it][1], 0, 0, 0);
        }
    }
    float* pz = pacc + (long)z * PSLAB;
    int mbase = m0w + 4 * kg;
#pragma unroll
    for (int it = 0; it < 4; ++it) {
#pragma unroll
        for (int ct = 0; ct < 2; ++ct) {
            int c = ct * 16 + cl;
            if (c < 22) {
                float* dst = pz + ((long)(b * 4 + it) * 22 + c) * WHP + mbase;
                if (mbase + 3 < WH) {
                    *(f32x4*)dst = accv[it][ct];
                } else {
#pragma unroll
                    for (int r = 0; r < 4; ++r)
                        if (mbase + r < WH) dst[r] = accv[it][ct][r];
                }
            }
        }
    }
}

// wcum[b][it][c][m] = (sum_z pacc[z][c][m]) / (sum_z pacc[z][21][m]) + Kc[c]
__global__ void k_dfin(const float* __restrict__ pacc, const float* __restrict__ Kc,
                       float* __restrict__ wcum) {
    int gid = blockIdx.x * blockDim.x + threadIdx.x;
    if (gid >= BS * 4 * NCLS * WH) return;
    int m = gid % WH;
    int t = gid / WH;
    int c = t % NCLS; t /= NCLS;
    int it = t & 3;
    int b = t >> 2;
    long rowc = ((long)(b * 4 + it) * 22 + c) * WHP + m;
    long rown = ((long)(b * 4 + it) * 22 + NCLS) * WHP + m;
    float num = 0.f, cnt = 0.f;
#pragma unroll
    for (int z = 0; z < NZ; ++z) {
        num += pacc[(long)z * PSLAB + rowc];
        cnt += pacc[(long)z * PSLAB + rown];
    }
    wcum[(((long)b * 4 + it) * NCLS + c) * WH + m] = num / cnt + Kc[c];
}

// per-(b,m): scale-softmax mask, fused logits, two 21-way softmaxes. grid 106 x 64
__global__ void k_mask(const float* __restrict__ wcum, const float* __restrict__ smw,
                       float* __restrict__ out_wc2, float* __restrict__ out_wei,
                       float* __restrict__ out_mask) {
    int gid = blockIdx.x * blockDim.x + threadIdx.x;
    if (gid >= BS * WH) return;
    int b = gid / WH, m = gid - b * WH;
    const float* base = wcum + (long)b * 4 * NCLS * WH + m;

    float fused[21];
#pragma unroll
    for (int c = 0; c < NCLS; ++c) {
        float sc = smw[c];
        float L0 = base[(0 * NCLS + c) * WH];
        float L1 = base[(1 * NCLS + c) * WH];
        float L2 = base[(2 * NCLS + c) * WH];
        float L3 = base[(3 * NCLS + c) * WH];
        float a0 = sc * L0, a1 = sc * L1, a2 = sc * L2, a3 = sc * L3;
        float mx = fmaxf(fmaxf(a0, a1), fmaxf(a2, a3));
        float e0 = __expf(a0 - mx), e1 = __expf(a1 - mx), e2 = __expf(a2 - mx), e3 = __expf(a3 - mx);
        float inv = 1.0f / (e0 + e1 + e2 + e3);
        e0 *= inv; e1 *= inv; e2 *= inv; e3 *= inv;
        out_mask[((long)(b * 4 + 0) * NCLS + c) * WH + m] = e0;
        out_mask[((long)(b * 4 + 1) * NCLS + c) * WH + m] = e1;
        out_mask[((long)(b * 4 + 2) * NCLS + c) * WH + m] = e2;
        out_mask[((long)(b * 4 + 3) * NCLS + c) * WH + m] = e3;
        fused[c] = L0 * e0 + L1 * e1 + L2 * e2 + L3 * e3;
    }
    float mx = -1e30f;
#pragma unroll
    for (int c = 0; c < NCLS; ++c) mx = fmaxf(mx, fused[c]);
    float s = 0.f;
    float e[21];
#pragma unroll
    for (int c = 0; c < NCLS; ++c) { e[c] = __expf(fused[c] - mx); s += e[c]; }
    float inv = 1.0f / s;
#pragma unroll
    for (int c = 0; c < NCLS; ++c) {
        e[c] *= inv;
        out_wc2[((long)b * NCLS + c) * WH + m] = e[c];
    }
    mx = -1e30f;
#pragma unroll
    for (int c = 0; c < NCLS; ++c) mx = fmaxf(mx, e[c]);
    s = 0.f;
    float e2a[21];
#pragma unroll
    for (int c = 0; c < NCLS; ++c) { e2a[c] = __expf(e[c] - mx); s += e2a[c]; }
    inv = 1.0f / s;
#pragma unroll
    for (int c = 0; c < NCLS; ++c) out_wei[((long)b * NCLS + c) * WH + m] = e2a[c] * inv;
}

// per-(b,c): softmax-pool over m with g, sigmoid. grid (21,4) x 256
__global__ void k_pool(const float* __restrict__ wei, const float* __restrict__ g,
                       const float* __restrict__ poolw, const float* __restrict__ Kc,
                       float* __restrict__ prob) {
    int c = blockIdx.x, b = blockIdx.y;
    const float* wr = wei + ((long)b * NCLS + c) * WH;
    const float* gr = g + ((long)b * NCLS + c) * WH;
    float E = __expf(poolw[c]);
    __shared__ float red[256];
    float mx = -1e30f;
    for (int m = threadIdx.x; m < WH; m += 256) mx = fmaxf(mx, wr[m] * E);
    red[threadIdx.x] = mx; __syncthreads();
    for (int o = 128; o > 0; o >>= 1) {
        if (threadIdx.x < o) red[threadIdx.x] = fmaxf(red[threadIdx.x], red[threadIdx.x + o]);
        __syncthreads();
    }
    mx = red[0]; __syncthreads();
    float se = 0.f, sg = 0.f;
    for (int m = threadIdx.x; m < WH; m += 256) {
        float ev = __expf(wr[m] * E - mx);
        se += ev; sg += ev * gr[m];
    }
    red[threadIdx.x] = se; __syncthreads();
    for (int o = 128; o > 0; o >>= 1) {
        if (threadIdx.x < o) red[threadIdx.x] += red[threadIdx.x + o];
        __syncthreads();
    }
    se = red[0]; __syncthreads();
    red[threadIdx.x] = sg; __syncthreads();
    for (int o = 128; o > 0; o >>= 1) {
        if (threadIdx.x < o) red[threadIdx.x] += red[threadIdx.x + o];
        __syncthreads();
    }
    sg = red[0];
    if (threadIdx.x == 0) {
        float out = sg / se + Kc[c];
        prob[b * NCLS + c] = 1.0f / (1.0f + __expf(-out));
    }
}

// ---------------- launcher ----------------
extern "C" void kernel_launch(void* const* d_in, const int* in_sizes, int n_in,
                              void* d_out, int out_size, void* d_ws, size_t ws_size,
                              hipStream_t stream) {
    const float* x      = (const float*)d_in[0];
    const float* diffW  = (const float*)d_in[1];
    const float* conv_w = (const float*)d_in[2];
    const float* conv_b = (const float*)d_in[3];
    const float* cls_w  = (const float*)d_in[4];
    const float* cls_b  = (const float*)d_in[5];
    const float* smw    = (const float*)d_in[6];
    const float* poolw  = (const float*)d_in[7];
    const float* msc    = (const float*)d_in[8];

    float* ws   = (float*)d_ws;
    float* Kc   = ws + WS_KC;
    float* Hp   = ws + WS_H2;
    float* wcum = ws + WS_WCUM;
    float* g    = ws + WS_G;
    unsigned short* Gsw  = (unsigned short*)(ws + WS_GSW);
    float* pmrg = ws + WS_W2P;
    float* pacc = ws + WS_W2P;            // aliases pmrg (dead once w2mb packed)
    unsigned short* w2mb = (unsigned short*)(ws + WS_W2MB);

    float* out  = (float*)d_out;
    float* o_prob = out;                       // [4][1][21]
    float* o_wc2  = out + 84;                  // [4][21][1681]
    float* o_wei  = out + 84 + 141204;         // [4][21][1681]
    float* o_mask = out + 84 + 141204 + 141204;// [4][4][21][1681]

    k_const<<<NCLS, 256, 0, stream>>>(cls_w, conv_b, cls_b, Kc);
    k_mergemm<<<dim3(KPOS / 64, MKZ), 256, 0, stream>>>(cls_w, conv_w, pmrg);
    k_mfinpack<<<(64 * 12 * 64 + 255) / 256, 256, 0, stream>>>(pmrg, w2mb);
    k_gemmm<<<dim3(18, BS, 4), 256, 0, stream>>>(w2mb, x, Hp);
    k_combine<<<(BS * NCLS * WH + 255) / 256, 256, 0, stream>>>(Hp, g);
    k_gpack<<<(BS * NT * 2 * 64 + 255) / 256, 256, 0, stream>>>(g, Gsw);
    k_dgemm<<<dim3(27, BS, NZ), 256, 0, stream>>>(diffW, Gsw, msc, pacc);
    k_dfin<<<(BS * 4 * NCLS * WH + 255) / 256, 256, 0, stream>>>(pacc, Kc, wcum);
    k_mask<<<(BS * WH + 63) / 64, 64, 0, stream>>>(wcum, smw, o_wc2, o_wei, o_mask);
    k_pool<<<dim3(NCLS, BS), 256, 0, stream>>>(o_wei, g, poolw, Kc, o_prob);
}

// Round 18
// 94.747 us; speedup vs baseline: 1.9262x; 1.0823x over previous
//
#include <hip/hip_runtime.h>
#include <hip/hip_bf16.h>
#include <math.h>

#define NCLS 21
#define WH 1681          // 41*41
#define WHP 1684         // padded row stride for pacc (16B-aligned float4 stores)
#define BS 4
#define CIN 2048
#define NSRC 1089        // 33*33
#define KPOS 18432       // 2048*9
#define MR 192           // 21*9=189 padded to 192
#define HS 836352        // one k-split slab of Hp
#define NT 53            // ceil(1681/32) K-tiles for diffusion GEMM
#define NZ 8             // diffusion GEMM k-splits (non-atomic slabs)
#define PSLAB (16L * 22L * WHP)   // 592,768 floats per z-slab
#define MKZ 4            // merge-GEMM k-splits
#define MSLAB (32L * KPOS)        // 589,824 floats per merge partial slab

typedef __attribute__((ext_vector_type(8))) __bf16 bf16x8;
typedef __attribute__((ext_vector_type(4))) float f32x4;

// ---------------- ws layout (floats) ----------------
#define WS_KC    393216L                  // 32
#define WS_H2    393248L                  // 4 slabs x 836,352 = 3,345,408
#define WS_WCUM  (WS_H2 + 4L * HS)        // 564,816
#define WS_G     (WS_WCUM + 564816L)      // 141,204
#define WS_GSW   (WS_G + 141204L)         // 108,544 (bf16 x 217,088)
#define WS_CF    (WS_GSW + 108544L)       // 16,384 (bf16 x 32,768) cls fragments
#define WS_W2P   (WS_CF + 591712L)        // pmrg 4 x 589,824 ; pacc aliases (8*592,768 fits)
#define WS_W2MB  (WS_W2P + 6193152L)      // 196,608 (bf16 x 393,216)

static __device__ __forceinline__ unsigned short f2bf(float v) {
    unsigned int b = __float_as_uint(v);
    b += 0x7FFFu + ((b >> 16) & 1u);
    return (unsigned short)(b >> 16);
}

// ---------------- kernels ----------------

// fused prep: blocks 0..15 pack cls_w bf16 A-fragments; blocks 16..36 compute Kc.
__global__ void k_prep(const float* __restrict__ clsw, const float* __restrict__ convb,
                       const float* __restrict__ clsb, unsigned short* __restrict__ cf,
                       float* __restrict__ Kc) {
    if (blockIdx.x < 16) {
        int gid = blockIdx.x * 256 + threadIdx.x;   // < 32*2*64 = 4096
        int lane = gid & 63;
        int rt = (gid >> 6) & 1;
        int kc = gid >> 7;
        int cl = lane & 15, kg = lane >> 4;
        int c = rt * 16 + cl;
        unsigned short o[8];
#pragma unroll
        for (int j = 0; j < 8; ++j) {
            int d = kc * 32 + kg * 8 + j;
            o[j] = (c < NCLS) ? f2bf(clsw[c * 1024 + d]) : (unsigned short)0;
        }
        unsigned short* p = cf + (long)gid * 8;
#pragma unroll
        for (int j = 0; j < 8; ++j) p[j] = o[j];
    } else {
        __shared__ float red[256];
        int c = blockIdx.x - 16;
        float s = 0.f;
        for (int d = threadIdx.x; d < 1024; d += 256) s += clsw[c * 1024 + d] * convb[d];
        red[threadIdx.x] = s; __syncthreads();
        for (int o = 128; o > 0; o >>= 1) {
            if (threadIdx.x < o) red[threadIdx.x] += red[threadIdx.x + o];
            __syncthreads();
        }
        if (threadIdx.x == 0) Kc[c] = red[0] + clsb[c];
    }
}

#define LOADC(dst, ch) { const float* cc_ = cb + (long)((ch) * 32 + wv * 8) * KPOS; \
    _Pragma("unroll") for (int jj = 0; jj < 8; ++jj) dst[jj] = cc_[(long)jj * KPOS]; }

// MFMA merge GEMM: pmrg[kz][c][pos] = sum_{d in kz-split} cls_w[c,d]*conv_w[d,pos]
// grid (288, 4) x 256; 2-deep register prefetch of conv_w chunks; cf-prepacked A
__global__ __launch_bounds__(256) void k_mergemm(const unsigned short* __restrict__ cf,
                                                 const float* __restrict__ convw,
                                                 float* __restrict__ pmrg) {
    __shared__ unsigned short Bs[2][64][40];
    int tid = threadIdx.x;
    int lane = tid & 63, wv = tid >> 6;
    int kg = lane >> 4, cl = lane & 15;
    int pos0 = blockIdx.x * 64;
    int kz = blockIdx.y;

    const float* cb = convw + (long)(kz * 256) * KPOS + pos0 + lane;

    f32x4 acc[2];
#pragma unroll
    for (int i = 0; i < 2; ++i) acc[i] = (f32x4){0.f, 0.f, 0.f, 0.f};

    float xr0[8], xr1[8], xrn[8];
    LOADC(xr0, 0);
    LOADC(xr1, 1);
    for (int ch = 0; ch < 8; ++ch) {
        if (ch + 2 < 8) LOADC(xrn, ch + 2);
        bf16x8 afr[2];
        const unsigned short* ab = cf + (((long)(kz * 8 + ch) * 2) * 64 + lane) * 8;
#pragma unroll
        for (int i = 0; i < 2; ++i) afr[i] = *(const bf16x8*)(ab + (long)i * 64 * 8);
        union { unsigned short u[8]; bf16x8 v; } bw;
#pragma unroll
        for (int jj = 0; jj < 8; ++jj) bw.u[jj] = f2bf(xr0[jj]);
        int buf = ch & 1;
        *(bf16x8*)&Bs[buf][lane][wv * 8] = bw.v;
        __syncthreads();
        bf16x8 bf = *(const bf16x8*)&Bs[buf][wv * 16 + cl][kg * 8];
#pragma unroll
        for (int i = 0; i < 2; ++i)
            acc[i] = __builtin_amdgcn_mfma_f32_16x16x32_bf16(afr[i], bf, acc[i], 0, 0, 0);
#pragma unroll
        for (int jj = 0; jj < 8; ++jj) { xr0[jj] = xr1[jj]; xr1[jj] = xrn[jj]; }
    }
    float* pz = pmrg + (long)kz * MSLAB;
    int pos = pos0 + wv * 16 + cl;
#pragma unroll
    for (int i = 0; i < 2; ++i) {
#pragma unroll
        for (int rr = 0; rr < 4; ++rr) {
            int c = i * 16 + 4 * kg + rr;
            pz[(long)c * KPOS + pos] = acc[i][rr];
        }
    }
}

// fused finisher: sum merge slabs, transpose pos=(i,t)->[r][i], pack bf16 A-fragments.
__global__ void k_mfinpack(const float* __restrict__ pmrg, unsigned short* __restrict__ w2mb) {
    int gid = blockIdx.x * blockDim.x + threadIdx.x;
    if (gid >= 64 * 12 * 64) return;
    int lane = gid & 63;
    int rt = (gid >> 6) % 12;
    int kc = gid / (64 * 12);
    int cl = lane & 15, kg = lane >> 4;
    int r = rt * 16 + cl;
    unsigned short o[8];
    if (r < 189) {
        int c = r / 9, t = r - c * 9;
        const float* base = pmrg + (long)c * KPOS + t;
#pragma unroll
        for (int j = 0; j < 8; ++j) {
            int i = kc * 32 + kg * 8 + j;
            long pos = (long)i * 9;
            float s = 0.f;
#pragma unroll
            for (int kz = 0; kz < MKZ; ++kz) s += base[(long)kz * MSLAB + pos];
            o[j] = f2bf(s);
        }
    } else {
#pragma unroll
        for (int j = 0; j < 8; ++j) o[j] = 0;
    }
    unsigned short* p = w2mb + (long)gid * 8;
#pragma unroll
    for (int j = 0; j < 8; ++j) p[j] = o[j];
}

#define LOADX(dst, ch) { const float* xc_ = xb + (long)((ch) * 32 + wv * 8) * NSRC; \
    _Pragma("unroll") for (int jj = 0; jj < 8; ++jj) dst[jj] = nok ? xc_[(long)jj * NSRC] : 0.f; }

// MFMA main GEMM: Hp[ks][b][r][n] = sum_{k in ks-split} w2m[r][k] * x[b][k][n]
__global__ __launch_bounds__(256) void k_gemmm(const unsigned short* __restrict__ w2mb,
                                               const float* __restrict__ x,
                                               float* __restrict__ Hp) {
    __shared__ unsigned short Bs[2][64][40];
    int tid = threadIdx.x;
    int lane = tid & 63, wv = tid >> 6;
    int kg = lane >> 4, cl = lane & 15;
    int n0 = blockIdx.x * 64;
    int b  = blockIdx.y;
    int ks = blockIdx.z;

    const float* xb = x + ((long)b * CIN + ks * 512) * NSRC + n0 + lane;
    bool nok = (n0 + lane) < NSRC;

    f32x4 acc[3][4];
#pragma unroll
    for (int i = 0; i < 3; ++i)
#pragma unroll
        for (int ct = 0; ct < 4; ++ct) acc[i][ct] = (f32x4){0.f, 0.f, 0.f, 0.f};

    float xr0[8], xr1[8], xrn[8];
    LOADX(xr0, 0);
    LOADX(xr1, 1);
    for (int ch = 0; ch < 16; ++ch) {
        if (ch + 2 < 16) LOADX(xrn, ch + 2);
        bf16x8 afr[3];
        const unsigned short* wb = w2mb + (((long)(ks * 16 + ch) * 12 + wv * 3) * 64 + lane) * 8;
#pragma unroll
        for (int i = 0; i < 3; ++i) afr[i] = *(const bf16x8*)(wb + (long)i * 64 * 8);
        union { unsigned short u[8]; bf16x8 v; } bw;
#pragma unroll
        for (int jj = 0; jj < 8; ++jj) bw.u[jj] = f2bf(xr0[jj]);
        int buf = ch & 1;
        *(bf16x8*)&Bs[buf][lane][wv * 8] = bw.v;
        __syncthreads();
#pragma unroll
        for (int ct = 0; ct < 4; ++ct) {
            bf16x8 bf = *(const bf16x8*)&Bs[buf][ct * 16 + cl][kg * 8];
#pragma unroll
            for (int i = 0; i < 3; ++i)
                acc[i][ct] = __builtin_amdgcn_mfma_f32_16x16x32_bf16(afr[i], bf, acc[i][ct], 0, 0, 0);
        }
#pragma unroll
        for (int jj = 0; jj < 8; ++jj) { xr0[jj] = xr1[jj]; xr1[jj] = xrn[jj]; }
    }
    float* Hb = Hp + (long)ks * HS + (long)b * MR * NSRC;
#pragma unroll
    for (int i = 0; i < 3; ++i) {
        int r0 = (wv * 3 + i) * 16 + 4 * kg;
#pragma unroll
        for (int ct = 0; ct < 4; ++ct) {
            int n = n0 + ct * 16 + cl;
            if (n < NSRC) {
#pragma unroll
                for (int rr = 0; rr < 4; ++rr)
                    Hb[(long)(r0 + rr) * NSRC + n] = acc[i][ct][rr];
            }
        }
    }
}

// g[b][c][m] = sum_t ok(m,t) * Bilinear41->33(H[b][c*9+t]); H = sum of 4 slabs
__global__ void k_combine(const float* __restrict__ Hp, float* __restrict__ g) {
    int gid = blockIdx.x * blockDim.x + threadIdx.x;
    if (gid >= BS * NCLS * WH) return;
    int m = gid % WH;
    int t_ = gid / WH;
    int c = t_ % NCLS;
    int b = t_ / NCLS;
    int yy = m / 41, xx = m - yy * 41;
    const float S = 33.0f / 41.0f;
    int y0a[3], y1a[3], x0a[3], x1a[3];
    float wya[3], wxa[3];
    bool oky[3], okx[3];
#pragma unroll
    for (int o = 0; o < 3; ++o) {
        int yp = yy + 6 * o - 6;
        oky[o] = (yp >= 0 && yp < 41);
        float sy = (yp + 0.5f) * S - 0.5f;
        float fy = floorf(sy);
        wya[o] = sy - fy;
        int y0 = (int)fy;
        y0a[o] = min(max(y0, 0), 32);
        y1a[o] = min(max(y0 + 1, 0), 32);
        int xp = xx + 6 * o - 6;
        okx[o] = (xp >= 0 && xp < 41);
        float sx = (xp + 0.5f) * S - 0.5f;
        float fx = floorf(sx);
        wxa[o] = sx - fx;
        int x0 = (int)fx;
        x0a[o] = min(max(x0, 0), 32);
        x1a[o] = min(max(x0 + 1, 0), 32);
    }
    float acc = 0.f;
    const float* Hb = Hp + ((long)b * MR + c * 9) * NSRC;
#pragma unroll
    for (int ty = 0; ty < 3; ++ty) {
#pragma unroll
        for (int tx = 0; tx < 3; ++tx) {
            if (oky[ty] && okx[tx]) {
                const float* hr = Hb + (ty * 3 + tx) * NSRC;
                int i00 = y0a[ty] * 33 + x0a[tx], i01 = y0a[ty] * 33 + x1a[tx];
                int i10 = y1a[ty] * 33 + x0a[tx], i11 = y1a[ty] * 33 + x1a[tx];
                float v00 = 0.f, v01 = 0.f, v10 = 0.f, v11 = 0.f;
#pragma unroll
                for (int s = 0; s < 4; ++s) {
                    const float* h2 = hr + (long)s * HS;
                    v00 += h2[i00]; v01 += h2[i01]; v10 += h2[i10]; v11 += h2[i11];
                }
                float wy = wya[ty], wx = wxa[tx];
                float v0 = v00 + wx * (v01 - v00);
                float v1 = v10 + wx * (v11 - v10);
                acc += v0 + wy * (v1 - v0);
            }
        }
    }
    g[gid] = acc;
}

// pack g^T (bf16) into MFMA B-fragment order, plus ones column (col 21).
__global__ void k_gpack(const float* __restrict__ g, unsigned short* __restrict__ Gsw) {
    int gid = blockIdx.x * blockDim.x + threadIdx.x;
    if (gid >= BS * NT * 2 * 64) return;
    int lane = gid & 63;
    int t = gid >> 6;
    int ct = t & 1; t >>= 1;
    int nt = t % NT;
    int b  = t / NT;
    int col = ct * 16 + (lane & 15);
    int nb = nt * 32 + (lane >> 4) * 8;
    unsigned short out[8];
#pragma unroll
    for (int j = 0; j < 8; ++j) {
        int n = nb + j;
        unsigned short v = 0;
        if (n < WH) {
            if (col < NCLS) v = f2bf(g[((long)b * NCLS + col) * WH + n]);
            else if (col == NCLS) v = 0x3F80;
        }
        out[j] = v;
    }
    unsigned short* p = Gsw + (long)gid * 8;
#pragma unroll
    for (int j = 0; j < 8; ++j) p[j] = out[j];
}

// fused mask-GEMM with LDS-coalesced diffW staging
__global__ __launch_bounds__(256) void k_dgemm(const float* __restrict__ diffW,
                                               const unsigned short* __restrict__ Gsw,
                                               const float* __restrict__ msc,
                                               float* __restrict__ pacc) {
    __shared__ float Ds[2][64][36];
    int tid  = threadIdx.x;
    int lane = tid & 63, wv = tid >> 6;
    int b = blockIdx.y, z = blockIdx.z;
    int m0 = blockIdx.x * 64;
    int m0w = m0 + wv * 16;
    int kg = lane >> 4;
    int cl = lane & 15;
    float thr[4];
#pragma unroll
    for (int it = 0; it < 4; ++it) thr[it] = msc[it];
    int nt0 = (z * NT) / NZ;
    int nt1 = ((z + 1) * NT) / NZ;

    int scol = tid & 31;
    int srow = tid >> 5;
    long rb[8];
#pragma unroll
    for (int p = 0; p < 8; ++p) {
        int mr = m0 + srow + 8 * p; if (mr > WH - 1) mr = WH - 1;
        rb[p] = ((long)b * WH + mr) * WH;
    }
    const unsigned short* gb = Gsw + (long)b * NT * 2 * 64 * 8;

    f32x4 accv[4][2];
#pragma unroll
    for (int it = 0; it < 4; ++it)
#pragma unroll
        for (int ct = 0; ct < 2; ++ct) accv[it][ct] = (f32x4){0.f, 0.f, 0.f, 0.f};

    for (int nt = nt0; nt < nt1; ++nt) {
        int nb = nt * 32;
        int buf = nt & 1;
        int ncol = nb + scol;
        if (ncol <= WH - 1) {
#pragma unroll
            for (int p = 0; p < 8; ++p) Ds[buf][srow + 8 * p][scol] = diffW[rb[p] + ncol];
        } else {
#pragma unroll
            for (int p = 0; p < 8; ++p) Ds[buf][srow + 8 * p][scol] = -1e30f;
        }
        __syncthreads();

        float dw[8];
        const float* dsr = &Ds[buf][wv * 16 + cl][kg * 8];
#pragma unroll
        for (int j = 0; j < 8; ++j) dw[j] = dsr[j];

        union { unsigned short u[8]; bf16x8 v; } af[4];
#pragma unroll
        for (int it = 0; it < 4; ++it)
#pragma unroll
            for (int j = 0; j < 8; ++j)
                af[it].u[j] = (dw[j] > thr[it]) ? (unsigned short)0x3F80 : (unsigned short)0;

        const unsigned short* gp = gb + ((long)nt * 2 * 64 + lane) * 8;
        bf16x8 b0 = *(const bf16x8*)gp;
        bf16x8 b1 = *(const bf16x8*)(gp + 64 * 8);
#pragma unroll
        for (int it = 0; it < 4; ++it) {
            accv[it][0] = __builtin_amdgcn_mfma_f32_16x16x32_bf16(af[it].v, b0, accv[it][0], 0, 0, 0);
            accv[it][1] = __builtin_amdgcn_mfma_f32_16x16x32_bf16(af[it].v, b1, accv[it][1], 0, 0, 0);
        }
    }
    float* pz = pacc + (long)z * PSLAB;
    int mbase = m0w + 4 * kg;
#pragma unroll
    for (int it = 0; it < 4; ++it) {
#pragma unroll
        for (int ct = 0; ct < 2; ++ct) {
            int c = ct * 16 + cl;
            if (c < 22) {
                float* dst = pz + ((long)(b * 4 + it) * 22 + c) * WHP + mbase;
                if (mbase + 3 < WH) {
                    *(f32x4*)dst = accv[it][ct];
                } else {
#pragma unroll
                    for (int r = 0; r < 4; ++r)
                        if (mbase + r < WH) dst[r] = accv[it][ct][r];
                }
            }
        }
    }
}

// wcum[b][it][c][m] = (sum_z pacc[z][c][m]) / (sum_z pacc[z][21][m]) + Kc[c]
__global__ void k_dfin(const float* __restrict__ pacc, const float* __restrict__ Kc,
                       float* __restrict__ wcum) {
    int gid = blockIdx.x * blockDim.x + threadIdx.x;
    if (gid >= BS * 4 * NCLS * WH) return;
    int m = gid % WH;
    int t = gid / WH;
    int c = t % NCLS; t /= NCLS;
    int it = t & 3;
    int b = t >> 2;
    long rowc = ((long)(b * 4 + it) * 22 + c) * WHP + m;
    long rown = ((long)(b * 4 + it) * 22 + NCLS) * WHP + m;
    float num = 0.f, cnt = 0.f;
#pragma unroll
    for (int z = 0; z < NZ; ++z) {
        num += pacc[(long)z * PSLAB + rowc];
        cnt += pacc[(long)z * PSLAB + rown];
    }
    wcum[(((long)b * 4 + it) * NCLS + c) * WH + m] = num / cnt + Kc[c];
}

// per-(b,m): scale-softmax mask, fused logits, two 21-way softmaxes. grid 106 x 64
__global__ void k_mask(const float* __restrict__ wcum, const float* __restrict__ smw,
                       float* __restrict__ out_wc2, float* __restrict__ out_wei,
                       float* __restrict__ out_mask) {
    int gid = blockIdx.x * blockDim.x + threadIdx.x;
    if (gid >= BS * WH) return;
    int b = gid / WH, m = gid - b * WH;
    const float* base = wcum + (long)b * 4 * NCLS * WH + m;

    float fused[21];
#pragma unroll
    for (int c = 0; c < NCLS; ++c) {
        float sc = smw[c];
        float L0 = base[(0 * NCLS + c) * WH];
        float L1 = base[(1 * NCLS + c) * WH];
        float L2 = base[(2 * NCLS + c) * WH];
        float L3 = base[(3 * NCLS + c) * WH];
        float a0 = sc * L0, a1 = sc * L1, a2 = sc * L2, a3 = sc * L3;
        float mx = fmaxf(fmaxf(a0, a1), fmaxf(a2, a3));
        float e0 = __expf(a0 - mx), e1 = __expf(a1 - mx), e2 = __expf(a2 - mx), e3 = __expf(a3 - mx);
        float inv = 1.0f / (e0 + e1 + e2 + e3);
        e0 *= inv; e1 *= inv; e2 *= inv; e3 *= inv;
        out_mask[((long)(b * 4 + 0) * NCLS + c) * WH + m] = e0;
        out_mask[((long)(b * 4 + 1) * NCLS + c) * WH + m] = e1;
        out_mask[((long)(b * 4 + 2) * NCLS + c) * WH + m] = e2;
        out_mask[((long)(b * 4 + 3) * NCLS + c) * WH + m] = e3;
        fused[c] = L0 * e0 + L1 * e1 + L2 * e2 + L3 * e3;
    }
    float mx = -1e30f;
#pragma unroll
    for (int c = 0; c < NCLS; ++c) mx = fmaxf(mx, fused[c]);
    float s = 0.f;
    float e[21];
#pragma unroll
    for (int c = 0; c < NCLS; ++c) { e[c] = __expf(fused[c] - mx); s += e[c]; }
    float inv = 1.0f / s;
#pragma unroll
    for (int c = 0; c < NCLS; ++c) {
        e[c] *= inv;
        out_wc2[((long)b * NCLS + c) * WH + m] = e[c];
    }
    mx = -1e30f;
#pragma unroll
    for (int c = 0; c < NCLS; ++c) mx = fmaxf(mx, e[c]);
    s = 0.f;
    float e2a[21];
#pragma unroll
    for (int c = 0; c < NCLS; ++c) { e2a[c] = __expf(e[c] - mx); s += e2a[c]; }
    inv = 1.0f / s;
#pragma unroll
    for (int c = 0; c < NCLS; ++c) out_wei[((long)b * NCLS + c) * WH + m] = e2a[c] * inv;
}

// per-(b,c): softmax-pool over m with g, sigmoid. grid (21,4) x 256
__global__ void k_pool(const float* __restrict__ wei, const float* __restrict__ g,
                       const float* __restrict__ poolw, const float* __restrict__ Kc,
                       float* __restrict__ prob) {
    int c = blockIdx.x, b = blockIdx.y;
    const float* wr = wei + ((long)b * NCLS + c) * WH;
    const float* gr = g + ((long)b * NCLS + c) * WH;
    float E = __expf(poolw[c]);
    __shared__ float red[256];
    float mx = -1e30f;
    for (int m = threadIdx.x; m < WH; m += 256) mx = fmaxf(mx, wr[m] * E);
    red[threadIdx.x] = mx; __syncthreads();
    for (int o = 128; o > 0; o >>= 1) {
        if (threadIdx.x < o) red[threadIdx.x] = fmaxf(red[threadIdx.x], red[threadIdx.x + o]);
        __syncthreads();
    }
    mx = red[0]; __syncthreads();
    float se = 0.f, sg = 0.f;
    for (int m = threadIdx.x; m < WH; m += 256) {
        float ev = __expf(wr[m] * E - mx);
        se += ev; sg += ev * gr[m];
    }
    red[threadIdx.x] = se; __syncthreads();
    for (int o = 128; o > 0; o >>= 1) {
        if (threadIdx.x < o) red[threadIdx.x] += red[threadIdx.x + o];
        __syncthreads();
    }
    se = red[0]; __syncthreads();
    red[threadIdx.x] = sg; __syncthreads();
    for (int o = 128; o > 0; o >>= 1) {
        if (threadIdx.x < o) red[threadIdx.x] += red[threadIdx.x + o];
        __syncthreads();
    }
    sg = red[0];
    if (threadIdx.x == 0) {
        float out = sg / se + Kc[c];
        prob[b * NCLS + c] = 1.0f / (1.0f + __expf(-out));
    }
}

// ---------------- launcher ----------------
extern "C" void kernel_launch(void* const* d_in, const int* in_sizes, int n_in,
                              void* d_out, int out_size, void* d_ws, size_t ws_size,
                              hipStream_t stream) {
    const float* x      = (const float*)d_in[0];
    const float* diffW  = (const float*)d_in[1];
    const float* conv_w = (const float*)d_in[2];
    const float* conv_b = (const float*)d_in[3];
    const float* cls_w  = (const float*)d_in[4];
    const float* cls_b  = (const float*)d_in[5];
    const float* smw    = (const float*)d_in[6];
    const float* poolw  = (const float*)d_in[7];
    const float* msc    = (const float*)d_in[8];

    float* ws   = (float*)d_ws;
    float* Kc   = ws + WS_KC;
    float* Hp   = ws + WS_H2;
    float* wcum = ws + WS_WCUM;
    float* g    = ws + WS_G;
    unsigned short* Gsw  = (unsigned short*)(ws + WS_GSW);
    unsigned short* cf   = (unsigned short*)(ws + WS_CF);
    float* pmrg = ws + WS_W2P;
    float* pacc = ws + WS_W2P;            // aliases pmrg (dead once w2mb packed)
    unsigned short* w2mb = (unsigned short*)(ws + WS_W2MB);

    float* out  = (float*)d_out;
    float* o_prob = out;                       // [4][1][21]
    float* o_wc2  = out + 84;                  // [4][21][1681]
    float* o_wei  = out + 84 + 141204;         // [4][21][1681]
    float* o_mask = out + 84 + 141204 + 141204;// [4][4][21][1681]

    k_prep<<<37, 256, 0, stream>>>(cls_w, conv_b, cls_b, cf, Kc);
    k_mergemm<<<dim3(KPOS / 64, MKZ), 256, 0, stream>>>(cf, conv_w, pmrg);
    k_mfinpack<<<(64 * 12 * 64 + 255) / 256, 256, 0, stream>>>(pmrg, w2mb);
    k_gemmm<<<dim3(18, BS, 4), 256, 0, stream>>>(w2mb, x, Hp);
    k_combine<<<(BS * NCLS * WH + 255) / 256, 256, 0, stream>>>(Hp, g);
    k_gpack<<<(BS * NT * 2 * 64 + 255) / 256, 256, 0, stream>>>(g, Gsw);
    k_dgemm<<<dim3(27, BS, NZ), 256, 0, stream>>>(diffW, Gsw, msc, pacc);
    k_dfin<<<(BS * 4 * NCLS * WH + 255) / 256, 256, 0, stream>>>(pacc, Kc, wcum);
    k_mask<<<(BS * WH + 63) / 64, 64, 0, stream>>>(wcum, smw, o_wc2, o_wei, o_mask);
    k_pool<<<dim3(NCLS, BS), 256, 0, stream>>>(o_wei, g, poolw, Kc, o_prob);
}